// Round 3
// baseline (455.773 us; speedup 1.0000x reference)
//
#include <hip/hip_runtime.h>
#include <cfloat>
#include <stdint.h>

// Problem geometry (fixed by setup_inputs)
#define D       512
#define NCODES  1024
#define MROWS   32768          // 16 * 2048

// d_out layout (f32 elements): z_st, loss, dist, idx (idx stored as float)
#define ZST_OFF  0
#define LOSS_OFF 16777216
#define DIST_OFF 16777217ull
#define IDX_OFF  50331649

// ws layout: bytes [0, 2 MB) = split-E tile images; then f32 z2/e2/loss
// (float indices)
#define WS_Z2   524288
#define WS_E2   557056
#define WS_LOSS 558080

typedef __attribute__((ext_vector_type(4))) float f32x4;
typedef __attribute__((ext_vector_type(4))) int   i32x4;
typedef __bf16 bf16v8 __attribute__((ext_vector_type(8)));

static __device__ __forceinline__ uint32_t f2bf(float x) {
    // round-to-nearest-even bf16, low 16 bits
    uint32_t u = __float_as_uint(x);
    return (u + 0x7fffu + ((u >> 16) & 1u)) >> 16;
}
static __device__ __forceinline__ float bf2f(uint32_t h) {
    return __uint_as_float(h << 16);
}
static __device__ __forceinline__ f32x4 MFMA(bf16v8 a, bf16v8 b, f32x4 c) {
    return __builtin_amdgcn_mfma_f32_16x16x32_bf16(a, b, c, 0, 0, 0);
}

// ---------------------------------------------------------------------------
// e2 kernel: deterministic per-row ||e||^2 (argmin depends on e2, so no
// atomics here). One wave per emb row; 1024 waves.
// ---------------------------------------------------------------------------
__global__ void e2_kernel(const float* __restrict__ emb,
                          float* __restrict__ ws) {
    const int gw   = (int)((blockIdx.x * blockDim.x + threadIdx.x) >> 6);
    const int lane = threadIdx.x & 63;
    const float4* v = (const float4*)(emb + (size_t)gw * D);
    float4 a = v[lane * 2];
    float4 b = v[lane * 2 + 1];
    float s = a.x*a.x + a.y*a.y + a.z*a.z + a.w*a.w
            + b.x*b.x + b.y*b.y + b.z*b.z + b.w*b.w;
#pragma unroll
    for (int off = 32; off > 0; off >>= 1) s += __shfl_xor(s, off);
    if (lane == 0) ws[WS_E2 + gw] = s;
}

// ---------------------------------------------------------------------------
// Prepass: bf16 hi/lo split into global_load_lds-ready tile images, with
// fully coalesced 1 KB stores. One wave = 16 rows x one K=32 chunk (kt).
//   lane -> row r = lane>>2, k-chunk c = lane&3 (8 consecutive f32).
// Image layouts (per K=32 tile, 64 B rows, slot swizzle c ^ ((row>>1)&3)):
//   A (residual) -> z_st region of d_out: [bm 256][kt 16][comp 2][128r][64B]
//   B (emb)      -> ws:                   [nt 4][kt 16][comp 2][256r][64B]
// z2 accumulated via atomicAdd of per-kt partials (z2 is per-row constant ->
// never affects argmin; only dist values, at ~1e-4 scale).
// ---------------------------------------------------------------------------
__global__ void prepass_kernel(const float* __restrict__ residual,
                               const float* __restrict__ emb,
                               float* __restrict__ ws,
                               float* __restrict__ out) {
    const int gwave = (int)((blockIdx.x * blockDim.x + threadIdx.x) >> 6);
    const int lane  = threadIdx.x & 63;
    const int rowgroup = gwave >> 4;     // [0, 2112)
    const int kt       = gwave & 15;
    const int r = lane >> 2;             // 0..15
    const int c = lane & 3;              // 0..3
    const bool isA = rowgroup < (MROWS / 16);
    const int gr = isA ? rowgroup * 16 + r : (rowgroup - MROWS / 16) * 16 + r;
    const float* src = (isA ? residual : emb) + (size_t)gr * D + kt * 32 + c * 8;
    const float4 x0 = ((const float4*)src)[0];
    const float4 x1 = ((const float4*)src)[1];
    const float xs[8] = {x0.x, x0.y, x0.z, x0.w, x1.x, x1.y, x1.z, x1.w};
    uint32_t hp[4], lp[4];
    float s = 0.f;
#pragma unroll
    for (int i = 0; i < 4; ++i) {
        const float a = xs[2 * i], b = xs[2 * i + 1];
        s += a * a + b * b;
        const uint32_t h0 = f2bf(a), h1 = f2bf(b);
        const uint32_t l0 = f2bf(a - bf2f(h0)), l1 = f2bf(b - bf2f(h1));
        hp[i] = h0 | (h1 << 16);
        lp[i] = l0 | (l1 << 16);
    }
    if (isA) {
        // z2 partial over this wave's K=32 chunk: reduce the 4 lanes of a row
        float t = s;
        t += __shfl_xor(t, 1);
        t += __shfl_xor(t, 2);
        if (c == 0) atomicAdd(&ws[WS_Z2 + gr], t);
    }
    const i32x4 hv = {(int)hp[0], (int)hp[1], (int)hp[2], (int)hp[3]};
    const i32x4 lv = {(int)lp[0], (int)lp[1], (int)lp[2], (int)lp[3]};
    char* dst;
    int comp_stride;
    if (isA) {
        const int bm = gr >> 7, rl = gr & 127;
        const int slot = c ^ ((rl >> 1) & 3);
        dst = (char*)out + (size_t)bm * 262144 + (size_t)kt * 16384
            + rl * 64 + slot * 16;
        comp_stride = 8192;              // 128 rows * 64 B
    } else {
        const int nt = gr >> 8, cl = gr & 255;
        const int slot = c ^ ((cl >> 1) & 3);
        dst = (char*)ws + (size_t)nt * 524288 + (size_t)kt * 32768
            + cl * 64 + slot * 16;
        comp_stride = 16384;             // 256 rows * 64 B
    }
    *(i32x4*)dst = hv;
    *(i32x4*)(dst + comp_stride) = lv;
}

// ---------------------------------------------------------------------------
// Main kernel: 256 blocks x 512 threads (8 waves, 2(M) x 4(N)).
// Block tile 128 x 256 per nt sweep (4 sweeps). K split into 16 tiles of 32.
// 2-phase double-buffered pipeline: STAGE(s+1) issued BEFORE compute(s);
// single __syncthreads per tile (drains vmcnt with a full MFMA phase of
// latency cover). LDS = 2 x 48 KB buffers: [Ahi 8K][Alo 8K][Bhi 16K][Blo 16K].
// 3 bf16 products (hh, hl, lh) -> f32-accuracy dist.
// ---------------------------------------------------------------------------
__launch_bounds__(512, 2)
__global__ void vq_main_kernel(const float* __restrict__ residual,
                               const float* __restrict__ emb,
                               float* __restrict__ ws,
                               float* __restrict__ out) {
    __shared__ __align__(16) char smem[98304];
    const int tid  = threadIdx.x;
    const int wid  = tid >> 6, lane = tid & 63;
    const int ln15 = lane & 15, kg = lane >> 4;
    const int wm   = wid >> 2, wn = wid & 3;
    const int bm   = blockIdx.x;
    const int row0 = bm * 128;

    const char* Aimg = (const char*)out + (size_t)bm * 262144;  // split-R
    const char* Bimg = (const char*)ws;                         // split-E

    // frag LDS byte offsets within a 48 KB buffer (swizzled)
    int aoff[4], boff[4];
#pragma unroll
    for (int mf = 0; mf < 4; ++mf) {
        const int rA = wm * 64 + mf * 16 + ln15;
        aoff[mf] = rA * 64 + 16 * (kg ^ ((rA >> 1) & 3));
    }
#pragma unroll
    for (int nf = 0; nf < 4; ++nf) {
        const int cB = wn * 64 + nf * 16 + ln15;
        boff[nf] = 16384 + cB * 64 + 16 * (kg ^ ((cB >> 1) & 3));
    }

    float z2r[16];
#pragma unroll
    for (int mf = 0; mf < 4; ++mf)
#pragma unroll
        for (int j = 0; j < 4; ++j)
            z2r[mf * 4 + j] = ws[WS_Z2 + row0 + wm * 64 + mf * 16 + kg * 4 + j];

    float runv[16];
    int   runi[16];
#pragma unroll
    for (int li = 0; li < 16; ++li) { runv[li] = FLT_MAX; runi[li] = 0; }

    // stage tile s = nt*16 + kt into buf (48 KB): A 16 KB + B 32 KB
    auto STAGE = [&](int s, char* buf) {
        const int snt = s >> 4, skt = s & 15;
        const char* ga = Aimg + (size_t)skt * 16384 + wid * 1024 + lane * 16;
        char* la = buf + wid * 1024;
        __builtin_amdgcn_global_load_lds((const uint32_t*)ga, (uint32_t*)la, 16, 0, 0);
        __builtin_amdgcn_global_load_lds((const uint32_t*)(ga + 8192),
                                         (uint32_t*)(la + 8192), 16, 0, 0);
        const char* gb = Bimg + (size_t)snt * 524288 + (size_t)skt * 32768
                       + wid * 1024 + lane * 16;
        char* lb = buf + 16384 + wid * 1024;
#pragma unroll
        for (int i = 0; i < 4; ++i)
            __builtin_amdgcn_global_load_lds((const uint32_t*)(gb + i * 8192),
                                             (uint32_t*)(lb + i * 8192), 16, 0, 0);
    };

    STAGE(0, smem);   // prologue; first __syncthreads drains it

    for (int nt = 0; nt < 4; ++nt) {
        f32x4 acc[4][4];
#pragma unroll
        for (int mf = 0; mf < 4; ++mf)
#pragma unroll
            for (int nf = 0; nf < 4; ++nf) acc[mf][nf] = 0.f;

        for (int kt = 0; kt < 16; ++kt) {
            const int s = nt * 16 + kt;
            __syncthreads();   // buf[s&1] staged; buf[(s+1)&1] free of readers
            if (s < 63) STAGE(s + 1, smem + ((s + 1) & 1) * 49152);
            const char* buf = smem + (s & 1) * 49152;

            bf16v8 ah[4], al[4], bh[4], bl[4];
#pragma unroll
            for (int mf = 0; mf < 4; ++mf) {
                ah[mf] = *(const bf16v8*)(buf + aoff[mf]);
                al[mf] = *(const bf16v8*)(buf + aoff[mf] + 8192);
            }
#pragma unroll
            for (int nf = 0; nf < 4; ++nf) {
                bh[nf] = *(const bf16v8*)(buf + boff[nf]);
                bl[nf] = *(const bf16v8*)(buf + boff[nf] + 16384);
            }
#pragma unroll
            for (int mf = 0; mf < 4; ++mf)
#pragma unroll
                for (int nf = 0; nf < 4; ++nf) {
                    acc[mf][nf] = MFMA(ah[mf], bh[nf], acc[mf][nf]);
                    acc[mf][nf] = MFMA(ah[mf], bl[nf], acc[mf][nf]);
                    acc[mf][nf] = MFMA(al[mf], bh[nf], acc[mf][nf]);
                }

            if (kt == 15) {
                // epilogue for this nt: dist store + running argmin
                float e2v[4];
#pragma unroll
                for (int nf = 0; nf < 4; ++nf)
                    e2v[nf] = ws[WS_E2 + nt * 256 + wn * 64 + nf * 16 + ln15];
#pragma unroll
                for (int mf = 0; mf < 4; ++mf)
#pragma unroll
                    for (int nf = 0; nf < 4; ++nf)
#pragma unroll
                        for (int j = 0; j < 4; ++j) {
                            const float dv = (z2r[mf * 4 + j] + e2v[nf])
                                           - 2.0f * acc[mf][nf][j];
                            const int grow = row0 + wm * 64 + mf * 16 + kg * 4 + j;
                            const int gcol = nt * 256 + wn * 64 + nf * 16 + ln15;
                            out[DIST_OFF + (size_t)grow * 1024 + gcol] = dv;
                            const int li = mf * 4 + j;
                            if (dv < runv[li]) { runv[li] = dv; runi[li] = gcol; }
                        }
            }
        }
    }

    // argmin reduce across the 16 lanes sharing each row (vary ln15)
#pragma unroll
    for (int off = 1; off < 16; off <<= 1) {
#pragma unroll
        for (int li = 0; li < 16; ++li) {
            const float ov = __shfl_xor(runv[li], off);
            const int   oi = __shfl_xor(runi[li], off);
            if (ov < runv[li] || (ov == runv[li] && oi < runi[li])) {
                runv[li] = ov; runi[li] = oi;
            }
        }
    }

    // cross-wave (wn) combine via LDS
    float* smin = (float*)smem;            // [128][4]
    int*   sidx = (int*)(smem + 2048);     // [128][4]
    int*   srowcode = (int*)(smem + 4096); // [128]
    float* swsum = (float*)(smem + 4608);  // [8]
    __syncthreads();
    if (ln15 == 0) {
#pragma unroll
        for (int mf = 0; mf < 4; ++mf)
#pragma unroll
            for (int j = 0; j < 4; ++j) {
                const int rl = wm * 64 + mf * 16 + kg * 4 + j;
                smin[rl * 4 + wn] = runv[mf * 4 + j];
                sidx[rl * 4 + wn] = runi[mf * 4 + j];
            }
    }
    __syncthreads();
    if (tid < 128) {
        float bv = smin[tid * 4];
        int   bi = sidx[tid * 4];
#pragma unroll
        for (int c = 1; c < 4; ++c) {
            const float v  = smin[tid * 4 + c];
            const int   ci = sidx[tid * 4 + c];
            if (v < bv || (v == bv && ci < bi)) { bv = v; bi = ci; }
        }
        srowcode[tid] = bi;
        out[IDX_OFF + row0 + tid] = (float)bi;
    }
    __syncthreads();

    // z_st + loss partial (overwrites this block's split-R scratch)
    float lsum = 0.0f;
    for (int e4 = tid; e4 < 128 * 128; e4 += 512) {
        const int rl = e4 >> 7, dq = e4 & 127;
        const size_t gi = (size_t)(row0 + rl) * D + dq * 4;
        const float4 rv = *(const float4*)&residual[gi];
        const int code = srowcode[rl];
        const float4 ev = *(const float4*)&emb[(size_t)code * D + dq * 4];
        float4 st;
        const float dx = ev.x - rv.x, dy = ev.y - rv.y;
        const float dz = ev.z - rv.z, dw = ev.w - rv.w;
        st.x = rv.x + dx; st.y = rv.y + dy; st.z = rv.z + dz; st.w = rv.w + dw;
        *(float4*)&out[ZST_OFF + gi] = st;
        lsum += dx * dx + dy * dy + dz * dz + dw * dw;
    }
#pragma unroll
    for (int off = 32; off > 0; off >>= 1) lsum += __shfl_xor(lsum, off);
    if (lane == 0) swsum[wid] = lsum;
    __syncthreads();
    if (tid == 0) {
        float ssum = 0.0f;
#pragma unroll
        for (int w = 0; w < 8; ++w) ssum += swsum[w];
        atomicAdd(&ws[WS_LOSS], ssum);
    }
}

// ---------------------------------------------------------------------------
// Finalize: loss = (BETA + 1) * mean = 1.25 * sum / 16777216
// ---------------------------------------------------------------------------
__global__ void finalize_kernel(const float* __restrict__ ws,
                                float* __restrict__ out) {
    out[LOSS_OFF] = 1.25f * ws[WS_LOSS] / 16777216.0f;
}

extern "C" void kernel_launch(void* const* d_in, const int* in_sizes, int n_in,
                              void* d_out, int out_size, void* d_ws, size_t ws_size,
                              hipStream_t stream) {
    const float* residual = (const float*)d_in[0];
    const float* emb      = (const float*)d_in[1];
    float* out = (float*)d_out;
    float* ws  = (float*)d_ws;

    // zero z2/e2/loss region (prepass z2 uses atomicAdd; ws is poisoned 0xAA)
    hipMemsetAsync((char*)d_ws + (size_t)WS_Z2 * 4, 0,
                   (size_t)(MROWS + NCODES + 1) * 4, stream);
    prepass_kernel<<<8448, 256, 0, stream>>>(residual, emb, ws, out);
    e2_kernel<<<256, 256, 0, stream>>>(emb, ws);
    vq_main_kernel<<<MROWS / 128, 512, 0, stream>>>(residual, emb, ws, out);
    finalize_kernel<<<1, 1, 0, stream>>>(ws, out);
}

// Round 4
// 407.642 us; speedup vs baseline: 1.1181x; 1.1181x over previous
//
#include <hip/hip_runtime.h>
#include <cfloat>
#include <stdint.h>

// Problem geometry (fixed by setup_inputs)
#define D       512
#define NCODES  1024
#define MROWS   32768          // 16 * 2048

// d_out layout (f32 elements): z_st, loss, dist, idx (idx stored as float)
#define ZST_OFF  0
#define LOSS_OFF 16777216
#define DIST_OFF 16777217ull
#define IDX_OFF  50331649

// ws layout: bytes [0, 2 MB) = split-E image; then f32 e2[1024], loss[1]
#define WS_E2F   524288        // float index
#define WS_LOSSF 525312        // float index

typedef __attribute__((ext_vector_type(4))) float f32x4;
typedef __attribute__((ext_vector_type(4))) int   i32x4;
typedef __bf16 bf16v8 __attribute__((ext_vector_type(8)));

static __device__ __forceinline__ uint32_t f2bf(float x) {
    // round-to-nearest-even bf16, low 16 bits
    uint32_t u = __float_as_uint(x);
    return (u + 0x7fffu + ((u >> 16) & 1u)) >> 16;
}
static __device__ __forceinline__ float bf2f(uint32_t h) {
    return __uint_as_float(h << 16);
}
static __device__ __forceinline__ f32x4 MFMA(bf16v8 a, bf16v8 b, f32x4 c) {
    return __builtin_amdgcn_mfma_f32_16x16x32_bf16(a, b, c, 0, 0, 0);
}

// ---------------------------------------------------------------------------
// split-E: emb f32 -> bf16 hi/lo image, global_load_lds-ready.
// Image: [nblk 8][kstep 16][col 128][128 B row] ; row = 64 B hi | 64 B lo,
// 16 B slots XOR-swizzled by (col&7). One thread = one (row, kstep, half).
// Also zeroes the loss accumulator.
// ---------------------------------------------------------------------------
__global__ void split_e_kernel(const float* __restrict__ emb,
                               char* __restrict__ wsb,
                               float* __restrict__ wsf) {
    if (blockIdx.x == 0 && threadIdx.x == 0) wsf[WS_LOSSF] = 0.0f;
    const int u    = blockIdx.x * 256 + threadIdx.x;   // 0..32767
    const int row  = u >> 5;                           // 0..1023
    const int ks   = (u >> 1) & 15;
    const int half = u & 1;
    const float* p = emb + (size_t)row * D + ks * 32 + half * 16;
    float xs[16];
#pragma unroll
    for (int i = 0; i < 4; ++i) {
        const float4 v = ((const float4*)p)[i];
        xs[4*i] = v.x; xs[4*i+1] = v.y; xs[4*i+2] = v.z; xs[4*i+3] = v.w;
    }
    uint32_t hw[8], lw[8];
#pragma unroll
    for (int i = 0; i < 8; ++i) {
        const float a = xs[2*i], b = xs[2*i+1];
        const uint32_t h0 = f2bf(a), h1 = f2bf(b);
        const uint32_t l0 = f2bf(a - bf2f(h0)), l1 = f2bf(b - bf2f(h1));
        hw[i] = h0 | (h1 << 16);
        lw[i] = l0 | (l1 << 16);
    }
    const int nblk = row >> 7, col = row & 127;
    char* base = wsb + (size_t)nblk * 262144 + (size_t)ks * 16384 + col * 128;
    const int sw = col & 7;
    *(i32x4*)(base + 16 * ((half*2    ) ^ sw)) = i32x4{(int)hw[0],(int)hw[1],(int)hw[2],(int)hw[3]};
    *(i32x4*)(base + 16 * ((half*2 + 1) ^ sw)) = i32x4{(int)hw[4],(int)hw[5],(int)hw[6],(int)hw[7]};
    *(i32x4*)(base + 16 * ((4 + half*2    ) ^ sw)) = i32x4{(int)lw[0],(int)lw[1],(int)lw[2],(int)lw[3]};
    *(i32x4*)(base + 16 * ((4 + half*2 + 1) ^ sw)) = i32x4{(int)lw[4],(int)lw[5],(int)lw[6],(int)lw[7]};
}

// ---------------------------------------------------------------------------
// e2: deterministic per-row ||e||^2 (argmin depends on e2 -> no atomics).
// ---------------------------------------------------------------------------
__global__ void e2_kernel(const float* __restrict__ emb,
                          float* __restrict__ wsf) {
    const int gw   = (int)((blockIdx.x * blockDim.x + threadIdx.x) >> 6);
    const int lane = threadIdx.x & 63;
    const float4* v = (const float4*)(emb + (size_t)gw * D);
    const float4 a = v[lane * 2];
    const float4 b = v[lane * 2 + 1];
    float s = a.x*a.x + a.y*a.y + a.z*a.z + a.w*a.w
            + b.x*b.x + b.y*b.y + b.z*b.z + b.w*b.w;
#pragma unroll
    for (int off = 32; off > 0; off >>= 1) s += __shfl_xor(s, off);
    if (lane == 0) wsf[WS_E2F + gw] = s;
}

// ---------------------------------------------------------------------------
// GEMM: dist[m, n] = z2[m] + e2[n] - 2 * <r_m, e_n>, 3-product bf16 hi/lo.
// Grid 2048 = 256 M-blocks x 8 N-blocks, XCD-swizzled so the 8 N-blocks of
// an M-group share one XCD's L2 (residual fetched from HBM once).
// 256 threads = 4 waves (2x2), wave tile 64x64, BK=32 real k (128 B rows).
// A reg-staged from f32 residual (split on the fly, z2 for free);
// B via global_load_lds from the pre-swizzled image.
// 2-phase double buffer, one barrier per K-step; 2 blocks/CU resident.
// ---------------------------------------------------------------------------
__launch_bounds__(256, 2)
__global__ void gemm_kernel(const float* __restrict__ residual,
                            const char* __restrict__ wsb,
                            const float* __restrict__ wsf,
                            float* __restrict__ out) {
    __shared__ __align__(16) char smem[66048];   // 2 x (A 16K + B 16K) + z2s
    float* z2s = (float*)(smem + 65536);

    const int t    = threadIdx.x;
    const int lane = t & 63, wid = t >> 6;
    const int ln15 = lane & 15, kg = lane >> 4;
    const int wm   = wid >> 1, wn = wid & 1;

    // XCD-bijective swizzle: all 8 n-blocks of an m-group on one XCD
    const int bid  = blockIdx.x;
    const int xcd  = bid & 7, j = bid >> 3;
    const int mblk = xcd * 32 + (j >> 3);
    const int nblk = j & 7;
    const int row0 = mblk * 128;
    const int n0   = nblk * 128;

    // A staging role: thread owns (row = t>>1, half = t&1)
    const int arow = t >> 1, ahalf = t & 1;
    const float* asrc = residual + (size_t)(row0 + arow) * D + ahalf * 16;
    const int asw = arow & 7;
    char* awbase = nullptr;  // set per buffer

    // frag LDS byte offsets (within one 32 KB buffer)
    int aoffh[4], aoffl[4], boffh[4], boffl[4];
#pragma unroll
    for (int mf = 0; mf < 4; ++mf) {
        const int rA = wm * 64 + mf * 16 + ln15;
        aoffh[mf] = rA * 128 + 16 * ((    kg) ^ (rA & 7));
        aoffl[mf] = rA * 128 + 16 * ((4 + kg) ^ (rA & 7));
    }
#pragma unroll
    for (int nf = 0; nf < 4; ++nf) {
        const int cB = wn * 64 + nf * 16 + ln15;
        boffh[nf] = 16384 + cB * 128 + 16 * ((    kg) ^ (cB & 7));
        boffl[nf] = 16384 + cB * 128 + 16 * ((4 + kg) ^ (cB & 7));
    }

    const char* Bimg = wsb + (size_t)nblk * 262144;

    float z2p = 0.0f;

    auto LOAD_A = [&](int s, f32x4 na[4]) {
        const float* p = asrc + s * 32;
#pragma unroll
        for (int i = 0; i < 4; ++i) na[i] = *(const f32x4*)(p + 4 * i);
    };
    auto WRITE_A = [&](char* buf, const f32x4 na[4]) {
        float xs[16];
#pragma unroll
        for (int i = 0; i < 4; ++i) {
            xs[4*i] = na[i][0]; xs[4*i+1] = na[i][1];
            xs[4*i+2] = na[i][2]; xs[4*i+3] = na[i][3];
        }
        uint32_t hw[8], lw[8];
#pragma unroll
        for (int i = 0; i < 8; ++i) {
            const float a = xs[2*i], b = xs[2*i+1];
            z2p += a * a + b * b;
            const uint32_t h0 = f2bf(a), h1 = f2bf(b);
            const uint32_t l0 = f2bf(a - bf2f(h0)), l1 = f2bf(b - bf2f(h1));
            hw[i] = h0 | (h1 << 16);
            lw[i] = l0 | (l1 << 16);
        }
        char* base = buf + arow * 128;
        *(i32x4*)(base + 16 * ((ahalf*2    ) ^ asw)) = i32x4{(int)hw[0],(int)hw[1],(int)hw[2],(int)hw[3]};
        *(i32x4*)(base + 16 * ((ahalf*2 + 1) ^ asw)) = i32x4{(int)hw[4],(int)hw[5],(int)hw[6],(int)hw[7]};
        *(i32x4*)(base + 16 * ((4 + ahalf*2    ) ^ asw)) = i32x4{(int)lw[0],(int)lw[1],(int)lw[2],(int)lw[3]};
        *(i32x4*)(base + 16 * ((4 + ahalf*2 + 1) ^ asw)) = i32x4{(int)lw[4],(int)lw[5],(int)lw[6],(int)lw[7]};
    };
    auto STAGE_B = [&](int s, char* buf) {
        const char* gb = Bimg + (size_t)s * 16384 + wid * 4096 + lane * 16;
        char* lb = buf + 16384 + wid * 4096;
#pragma unroll
        for (int i = 0; i < 4; ++i)
            __builtin_amdgcn_global_load_lds((const uint32_t*)(gb + i * 1024),
                                             (uint32_t*)(lb + i * 1024), 16, 0, 0);
    };

    f32x4 acc[4][4];
#pragma unroll
    for (int mf = 0; mf < 4; ++mf)
#pragma unroll
        for (int nf = 0; nf < 4; ++nf) acc[mf][nf] = 0.f;

    // prologue: fill buffer 0
    {
        f32x4 na[4];
        LOAD_A(0, na);
        STAGE_B(0, smem);
        WRITE_A(smem, na);
    }

    for (int s = 0; s < 16; ++s) {
        __syncthreads();   // buf[s&1] complete; buf[(s+1)&1] free of readers
        char* nbuf = smem + ((s + 1) & 1) * 32768;
        f32x4 na[4];
        if (s < 15) {
            LOAD_A(s + 1, na);      // f32 -> regs (latency hidden under MFMA)
            STAGE_B(s + 1, nbuf);   // direct-to-LDS, drains at next barrier
        }
        const char* buf = smem + (s & 1) * 32768;

        bf16v8 ah[4], al[4], bh[4], bl[4];
#pragma unroll
        for (int mf = 0; mf < 4; ++mf) {
            ah[mf] = *(const bf16v8*)(buf + aoffh[mf]);
            al[mf] = *(const bf16v8*)(buf + aoffl[mf]);
        }
#pragma unroll
        for (int nf = 0; nf < 4; ++nf) {
            bh[nf] = *(const bf16v8*)(buf + boffh[nf]);
            bl[nf] = *(const bf16v8*)(buf + boffl[nf]);
        }
#pragma unroll
        for (int mf = 0; mf < 4; ++mf)
#pragma unroll
            for (int nf = 0; nf < 4; ++nf) {
                acc[mf][nf] = MFMA(ah[mf], bh[nf], acc[mf][nf]);
                acc[mf][nf] = MFMA(ah[mf], bl[nf], acc[mf][nf]);
                acc[mf][nf] = MFMA(al[mf], bh[nf], acc[mf][nf]);
            }

        if (s < 15) WRITE_A(nbuf, na);   // split + ds_write next A tile
    }

    // z2: combine the two halves of each staged row, publish to LDS
    __syncthreads();
    {
        const float o = __shfl_xor(z2p, 1);
        if (ahalf == 0) z2s[arow] = z2p + o;
    }
    __syncthreads();

    // epilogue: dist = z2 + e2 - 2*acc
    float e2v[4];
#pragma unroll
    for (int nf = 0; nf < 4; ++nf)
        e2v[nf] = wsf[WS_E2F + n0 + wn * 64 + nf * 16 + ln15];
#pragma unroll
    for (int mf = 0; mf < 4; ++mf)
#pragma unroll
        for (int j4 = 0; j4 < 4; ++j4) {
            const int rl = wm * 64 + mf * 16 + kg * 4 + j4;
            const float z2 = z2s[rl];
            const size_t rbase = DIST_OFF + (size_t)(row0 + rl) * 1024;
#pragma unroll
            for (int nf = 0; nf < 4; ++nf) {
                const int gcol = n0 + wn * 64 + nf * 16 + ln15;
                out[rbase + gcol] = (z2 + e2v[nf]) - 2.0f * acc[mf][nf][j4];
            }
        }
}

// ---------------------------------------------------------------------------
// argmin + z_st + loss: 512 blocks x 256 threads, 64 rows/block.
// Wave handles 16 rows; per row, 64 lanes scan 1024 dist values (coalesced
// 256 B per instruction), shfl-reduce with first-min tie-break.
// ---------------------------------------------------------------------------
__global__ void argzst_kernel(const float* __restrict__ residual,
                              const float* __restrict__ emb,
                              float* __restrict__ wsf,
                              float* __restrict__ out) {
    __shared__ int   srow[64];
    __shared__ float swsum[4];
    const int t = threadIdx.x, lane = t & 63, w = t >> 6;
    const int row0 = blockIdx.x * 64;

    for (int rr = 0; rr < 16; ++rr) {
        const int row = row0 + w * 16 + rr;
        const float* dr = out + DIST_OFF + (size_t)row * 1024;
        float lv = FLT_MAX; int li = 0;
#pragma unroll
        for (int c = 0; c < 16; ++c) {
            const int col = c * 64 + lane;
            const float v = dr[col];
            if (v < lv) { lv = v; li = col; }   // per-lane cols increase
        }
#pragma unroll
        for (int off = 32; off > 0; off >>= 1) {
            const float ov = __shfl_xor(lv, off);
            const int   oi = __shfl_xor(li, off);
            if (ov < lv || (ov == lv && oi < li)) { lv = ov; li = oi; }
        }
        if (lane == 0) {
            srow[w * 16 + rr] = li;
            out[IDX_OFF + row] = (float)li;
        }
    }
    __syncthreads();

    float lsum = 0.0f;
    for (int e4 = t; e4 < 64 * 128; e4 += 256) {
        const int rl = e4 >> 7, dq = e4 & 127;
        const size_t gi = (size_t)(row0 + rl) * D + dq * 4;
        const float4 rv = *(const float4*)&residual[gi];
        const int code = srow[rl];
        const float4 ev = *(const float4*)&emb[(size_t)code * D + dq * 4];
        float4 st;
        const float dx = ev.x - rv.x, dy = ev.y - rv.y;
        const float dz = ev.z - rv.z, dw = ev.w - rv.w;
        st.x = rv.x + dx; st.y = rv.y + dy; st.z = rv.z + dz; st.w = rv.w + dw;
        *(float4*)&out[ZST_OFF + gi] = st;
        lsum += dx * dx + dy * dy + dz * dz + dw * dw;
    }
#pragma unroll
    for (int off = 32; off > 0; off >>= 1) lsum += __shfl_xor(lsum, off);
    if (lane == 0) swsum[w] = lsum;
    __syncthreads();
    if (t == 0) {
        float s = 0.0f;
#pragma unroll
        for (int ww = 0; ww < 4; ++ww) s += swsum[ww];
        atomicAdd(&wsf[WS_LOSSF], s);
    }
}

// ---------------------------------------------------------------------------
// Finalize: loss = (BETA + 1) * mean = 1.25 * sum / 16777216
// ---------------------------------------------------------------------------
__global__ void finalize_kernel(const float* __restrict__ wsf,
                                float* __restrict__ out) {
    out[LOSS_OFF] = 1.25f * wsf[WS_LOSSF] / 16777216.0f;
}

extern "C" void kernel_launch(void* const* d_in, const int* in_sizes, int n_in,
                              void* d_out, int out_size, void* d_ws, size_t ws_size,
                              hipStream_t stream) {
    const float* residual = (const float*)d_in[0];
    const float* emb      = (const float*)d_in[1];
    float* out = (float*)d_out;
    char*  wsb = (char*)d_ws;
    float* wsf = (float*)d_ws;

    split_e_kernel<<<128, 256, 0, stream>>>(emb, wsb, wsf);
    e2_kernel<<<256, 256, 0, stream>>>(emb, wsf);
    gemm_kernel<<<2048, 256, 0, stream>>>(residual, wsb, wsf, out);
    argzst_kernel<<<512, 256, 0, stream>>>(residual, emb, wsf, out);
    finalize_kernel<<<1, 1, 0, stream>>>(wsf, out);
}

// Round 5
// 386.621 us; speedup vs baseline: 1.1789x; 1.0544x over previous
//
#include <hip/hip_runtime.h>
#include <cfloat>
#include <stdint.h>

// Problem geometry (fixed by setup_inputs)
#define D       512
#define NCODES  1024
#define MROWS   32768          // 16 * 2048

// d_out layout (f32 elements): z_st, loss, dist, idx (idx stored as float)
#define ZST_OFF  0
#define LOSS_OFF 16777216
#define DIST_OFF 16777217ull
#define IDX_OFF  50331649

// ws layout: bytes [0, 2 MB) = split-E image; then f32 e2[1024], z2[32768], loss
#define WS_E2F   524288                 // float index
#define WS_Z2F   (WS_E2F + 1024)
#define WS_LOSSF (WS_Z2F + MROWS)

typedef __attribute__((ext_vector_type(4))) float f32x4;
typedef __attribute__((ext_vector_type(4))) int   i32x4;
typedef __bf16 bf16v8 __attribute__((ext_vector_type(8)));

static __device__ __forceinline__ uint32_t f2bf(float x) {
    // round-to-nearest-even bf16, low 16 bits
    uint32_t u = __float_as_uint(x);
    return (u + 0x7fffu + ((u >> 16) & 1u)) >> 16;
}
static __device__ __forceinline__ float bf2f(uint32_t h) {
    return __uint_as_float(h << 16);
}
static __device__ __forceinline__ f32x4 MFMA(bf16v8 a, bf16v8 b, f32x4 c) {
    return __builtin_amdgcn_mfma_f32_16x16x32_bf16(a, b, c, 0, 0, 0);
}

// ---------------------------------------------------------------------------
// split-E: emb f32 -> bf16 hi/lo image, global_load_lds-ready.
// Image: [nblk 8][kstep 16][col 128][128 B row]; row = 8 x 16 B slots, content
// u at phys slot u ^ (col&7); u<4 = hi k-octet u, u>=4 = lo k-octet u-4.
// Also zeroes the loss accumulator.
// ---------------------------------------------------------------------------
__global__ void split_e_kernel(const float* __restrict__ emb,
                               char* __restrict__ wsb,
                               float* __restrict__ wsf) {
    if (blockIdx.x == 0 && threadIdx.x == 0) wsf[WS_LOSSF] = 0.0f;
    const int u    = blockIdx.x * 256 + threadIdx.x;   // 0..32767
    const int row  = u >> 5;                           // 0..1023
    const int ks   = (u >> 1) & 15;
    const int half = u & 1;
    const float* p = emb + (size_t)row * D + ks * 32 + half * 16;
    float xs[16];
#pragma unroll
    for (int i = 0; i < 4; ++i) {
        const float4 v = ((const float4*)p)[i];
        xs[4*i] = v.x; xs[4*i+1] = v.y; xs[4*i+2] = v.z; xs[4*i+3] = v.w;
    }
    uint32_t hw[8], lw[8];
#pragma unroll
    for (int i = 0; i < 8; ++i) {
        const float a = xs[2*i], b = xs[2*i+1];
        const uint32_t h0 = f2bf(a), h1 = f2bf(b);
        const uint32_t l0 = f2bf(a - bf2f(h0)), l1 = f2bf(b - bf2f(h1));
        hw[i] = h0 | (h1 << 16);
        lw[i] = l0 | (l1 << 16);
    }
    const int nblk = row >> 7, col = row & 127;
    char* base = wsb + (size_t)nblk * 262144 + (size_t)ks * 16384 + col * 128;
    const int sw = col & 7;
    *(i32x4*)(base + 16 * ((half*2    ) ^ sw)) = i32x4{(int)hw[0],(int)hw[1],(int)hw[2],(int)hw[3]};
    *(i32x4*)(base + 16 * ((half*2 + 1) ^ sw)) = i32x4{(int)hw[4],(int)hw[5],(int)hw[6],(int)hw[7]};
    *(i32x4*)(base + 16 * ((4 + half*2    ) ^ sw)) = i32x4{(int)lw[0],(int)lw[1],(int)lw[2],(int)lw[3]};
    *(i32x4*)(base + 16 * ((4 + half*2 + 1) ^ sw)) = i32x4{(int)lw[4],(int)lw[5],(int)lw[6],(int)lw[7]};
}

// ---------------------------------------------------------------------------
// norms: per-row ||.||^2 for residual (z2) then emb (e2). One wave per row.
// Deterministic (argmin depends on e2; z2 only shifts dist rows uniformly).
// Side effect: makes residual L3-resident right before the GEMM.
// ---------------------------------------------------------------------------
__global__ void norms_kernel(const float* __restrict__ residual,
                             const float* __restrict__ emb,
                             float* __restrict__ wsf) {
    const int gw   = (int)((blockIdx.x * blockDim.x + threadIdx.x) >> 6);
    const int lane = threadIdx.x & 63;
    const bool isR = gw < MROWS;
    const float* src = isR ? residual + (size_t)gw * D
                           : emb + (size_t)(gw - MROWS) * D;
    const float4* v = (const float4*)src;
    const float4 a = v[lane * 2];
    const float4 b = v[lane * 2 + 1];
    float s = a.x*a.x + a.y*a.y + a.z*a.z + a.w*a.w
            + b.x*b.x + b.y*b.y + b.z*b.z + b.w*b.w;
#pragma unroll
    for (int off = 32; off > 0; off >>= 1) s += __shfl_xor(s, off);
    if (lane == 0) {
        if (isR) wsf[WS_Z2F + gw] = s;
        else     wsf[WS_E2F + (gw - MROWS)] = s;
    }
}

// ---------------------------------------------------------------------------
// GEMM: dist[m,n] = z2[m] + e2[n] - 2<r_m, e_n>, 3-product bf16 hi/lo.
// Grid 2048 = 256 M-blocks x 8 N-blocks, XCD-bijective swizzle (R4: 65 MB
// fetch, keep). 256 threads = 4 waves (2M x 2N), wave tile 64x64, BK=32.
// LDS 49.7 KB -> 3 blocks/CU (12 waves): A single-buffer 16 KB (reg-staged,
// linear conflict-free ds_writes), B double-buffer 2x16 KB (global_load_lds
// from pre-swizzled image). All prefetch issues AFTER the visibility barrier
// so the next draining barrier is a full compute phase away.
// Epilogue: dist stores + per-wave-slab argmin partial (val,idx) stored in
// each row's own z_st slot (race-free; argzst overwrites later).
// ---------------------------------------------------------------------------
__launch_bounds__(256, 3)
__global__ void gemm_kernel(const float* __restrict__ residual,
                            const char* __restrict__ wsb,
                            const float* __restrict__ wsf,
                            float* __restrict__ out) {
    __shared__ __align__(16) char smem[49664];   // A 16K | B0 16K | B1 16K | z2s
    float* z2s = (float*)(smem + 49152);

    const int t    = threadIdx.x;
    const int lane = t & 63, wid = t >> 6;
    const int ln15 = lane & 15, kg = lane >> 4;
    const int wm   = wid >> 1, wn = wid & 1;

    // XCD-bijective swizzle: 8 n-blocks of an m-group share one XCD's L2
    const int bid  = blockIdx.x;
    const int xcd  = bid & 7, j = bid >> 3;
    const int mblk = xcd * 32 + (j >> 3);
    const int nblk = j & 7;
    const int row0 = mblk * 128;
    const int n0   = nblk * 128;

    // A staging map: thread t, write i -> LDS byte i*4096 + t*16 (linear!).
    //   row r = i*32 + (t>>3); phys slot = t&7; content u = (t&7) ^ (r&7).
    const int arb  = t >> 3;              // 0..31
    const int u    = (t & 7) ^ (arb & 7); // constant per thread
    const int comp = u >> 2, kq = u & 3;
    const float* aptr = residual + (size_t)(row0 + arb) * D + kq * 8;

    if (t < 128) z2s[t] = wsf[WS_Z2F + row0 + t];

    // frag LDS byte offsets
    int aoffh[4], aoffl[4], boffh[4], boffl[4];
#pragma unroll
    for (int mf = 0; mf < 4; ++mf) {
        const int rA = wm * 64 + mf * 16 + ln15;
        aoffh[mf] = rA * 128 + 16 * ((    kg) ^ (rA & 7));
        aoffl[mf] = rA * 128 + 16 * ((4 + kg) ^ (rA & 7));
    }
#pragma unroll
    for (int nf = 0; nf < 4; ++nf) {
        const int cB = wn * 64 + nf * 16 + ln15;
        boffh[nf] = cB * 128 + 16 * ((    kg) ^ (cB & 7));
        boffl[nf] = cB * 128 + 16 * ((4 + kg) ^ (cB & 7));
    }

    const char* Bimg = wsb + (size_t)nblk * 262144;

    float4 a0[4], a1[4];
    auto LOAD_A = [&](int s) {
#pragma unroll
        for (int i = 0; i < 4; ++i) {
            const float* p = aptr + (size_t)i * (32 * D) + s * 32;
            a0[i] = *(const float4*)p;
            a1[i] = *(const float4*)(p + 4);
        }
    };
    auto WRITE_A = [&]() {
#pragma unroll
        for (int i = 0; i < 4; ++i) {
            const float e[8] = {a0[i].x, a0[i].y, a0[i].z, a0[i].w,
                                a1[i].x, a1[i].y, a1[i].z, a1[i].w};
            uint32_t w[4];
#pragma unroll
            for (int jj = 0; jj < 4; ++jj) {
                const uint32_t h0 = f2bf(e[2*jj]), h1 = f2bf(e[2*jj+1]);
                uint32_t r;
                if (comp == 0) {
                    r = h0 | (h1 << 16);
                } else {
                    const uint32_t l0 = f2bf(e[2*jj]   - bf2f(h0));
                    const uint32_t l1 = f2bf(e[2*jj+1] - bf2f(h1));
                    r = l0 | (l1 << 16);
                }
                w[jj] = r;
            }
            *(i32x4*)(smem + i * 4096 + t * 16) =
                i32x4{(int)w[0], (int)w[1], (int)w[2], (int)w[3]};
        }
    };
    auto STAGE_B = [&](int s) {
        const char* gb = Bimg + (size_t)s * 16384 + t * 16;
        char* lb = smem + 16384 + (s & 1) * 16384 + t * 16;
#pragma unroll
        for (int i = 0; i < 4; ++i)
            __builtin_amdgcn_global_load_lds((const uint32_t*)(gb + i * 4096),
                                             (uint32_t*)(lb + i * 4096), 16, 0, 0);
    };

    f32x4 acc[4][4];
#pragma unroll
    for (int mf = 0; mf < 4; ++mf)
#pragma unroll
        for (int nf = 0; nf < 4; ++nf) acc[mf][nf] = 0.f;

    // prologue
    LOAD_A(0);
    STAGE_B(0);

    for (int s = 0; s < 16; ++s) {
        __syncthreads();            // drains A-regs(s) + B(s); A readers (s-1) done
        WRITE_A();                  // conflict-free linear ds_writes
        __syncthreads();            // A(s) visible in LDS
        if (s < 15) { LOAD_A(s + 1); STAGE_B(s + 1); }  // drain = next bar1

        const char* bbuf = smem + 16384 + (s & 1) * 16384;
        bf16v8 ah[4], al[4], bh[4], bl[4];
#pragma unroll
        for (int mf = 0; mf < 4; ++mf) {
            ah[mf] = *(const bf16v8*)(smem + aoffh[mf]);
            al[mf] = *(const bf16v8*)(smem + aoffl[mf]);
        }
#pragma unroll
        for (int nf = 0; nf < 4; ++nf) {
            bh[nf] = *(const bf16v8*)(bbuf + boffh[nf]);
            bl[nf] = *(const bf16v8*)(bbuf + boffl[nf]);
        }
#pragma unroll
        for (int mf = 0; mf < 4; ++mf)
#pragma unroll
            for (int nf = 0; nf < 4; ++nf) {
                acc[mf][nf] = MFMA(ah[mf], bh[nf], acc[mf][nf]);
                acc[mf][nf] = MFMA(ah[mf], bl[nf], acc[mf][nf]);
                acc[mf][nf] = MFMA(al[mf], bh[nf], acc[mf][nf]);
            }
    }

    // epilogue: dist stores + per-64-col-slab argmin partial
    float e2v[4];
#pragma unroll
    for (int nf = 0; nf < 4; ++nf)
        e2v[nf] = wsf[WS_E2F + n0 + wn * 64 + nf * 16 + ln15];
#pragma unroll
    for (int mf = 0; mf < 4; ++mf)
#pragma unroll
        for (int j4 = 0; j4 < 4; ++j4) {
            const int rl = wm * 64 + mf * 16 + kg * 4 + j4;
            const float z2 = z2s[rl];
            const size_t rbase = DIST_OFF + (size_t)(row0 + rl) * 1024;
            float bv = FLT_MAX; int bi = 0;
#pragma unroll
            for (int nf = 0; nf < 4; ++nf) {
                const int gcol = n0 + wn * 64 + nf * 16 + ln15;
                const float dv = (z2 + e2v[nf]) - 2.0f * acc[mf][nf][j4];
                out[rbase + gcol] = dv;
                if (dv < bv) { bv = dv; bi = gcol; }   // ascending col scan
            }
#pragma unroll
            for (int off = 1; off < 16; off <<= 1) {
                const float ov = __shfl_xor(bv, off);
                const int   oi = __shfl_xor(bi, off);
                if (ov < bv || (ov == bv && oi < bi)) { bv = ov; bi = oi; }
            }
            if (ln15 == 0) {
                // partial slot inside this row's own z_st space (overwritten
                // later by argzst, which owns the row)
                float2 pr; pr.x = bv; pr.y = (float)bi;
                *(float2*)&out[ZST_OFF + (size_t)(row0 + rl) * D
                               + (nblk * 2 + wn) * 2] = pr;
            }
        }
}

// ---------------------------------------------------------------------------
// argzst: reduce 16 argmin partials per row, then z_st + loss.
// 512 blocks x 256 threads, 64 rows/block; block touches only its own rows.
// ---------------------------------------------------------------------------
__global__ void argzst_kernel(const float* __restrict__ residual,
                              const float* __restrict__ emb,
                              float* __restrict__ wsf,
                              float* __restrict__ out) {
    __shared__ int   srow[64];
    __shared__ float swsum[4];
    const int t = threadIdx.x, lane = t & 63, w = t >> 6;
    const int row0 = blockIdx.x * 64;

    // phase 1: 4 rows per wave-instr, 16 slot-lanes per row
    const int rsub = lane >> 4;    // 0..3
    const int slot = lane & 15;    // ascending col order: slot = nblk*2 + wn
#pragma unroll
    for (int g = 0; g < 4; ++g) {
        const int rl  = w * 16 + g * 4 + rsub;
        const int row = row0 + rl;
        const float2 p = *(const float2*)&out[ZST_OFF + (size_t)row * D + slot * 2];
        float bv = p.x; float bif = p.y;
#pragma unroll
        for (int off = 1; off < 16; off <<= 1) {
            const float ov  = __shfl_xor(bv, off);
            const float oif = __shfl_xor(bif, off);
            if (ov < bv || (ov == bv && oif < bif)) { bv = ov; bif = oif; }
        }
        if (slot == 0) {
            srow[rl] = (int)bif;
            out[IDX_OFF + row] = bif;
        }
    }
    __syncthreads();

    // phase 2: z_st + loss partial (overwrites the partial slots)
    float lsum = 0.0f;
    for (int e4 = t; e4 < 64 * 128; e4 += 256) {
        const int rl = e4 >> 7, dq = e4 & 127;
        const size_t gi = (size_t)(row0 + rl) * D + dq * 4;
        const float4 rv = *(const float4*)&residual[gi];
        const int code = srow[rl];
        const float4 ev = *(const float4*)&emb[(size_t)code * D + dq * 4];
        float4 st;
        const float dx = ev.x - rv.x, dy = ev.y - rv.y;
        const float dz = ev.z - rv.z, dw = ev.w - rv.w;
        st.x = rv.x + dx; st.y = rv.y + dy; st.z = rv.z + dz; st.w = rv.w + dw;
        *(float4*)&out[ZST_OFF + gi] = st;
        lsum += dx * dx + dy * dy + dz * dz + dw * dw;
    }
#pragma unroll
    for (int off = 32; off > 0; off >>= 1) lsum += __shfl_xor(lsum, off);
    if (lane == 0) swsum[w] = lsum;
    __syncthreads();
    if (t == 0) {
        float s = 0.0f;
#pragma unroll
        for (int ww = 0; ww < 4; ++ww) s += swsum[ww];
        atomicAdd(&wsf[WS_LOSSF], s);
    }
}

// ---------------------------------------------------------------------------
// Finalize: loss = (BETA + 1) * mean = 1.25 * sum / 16777216
// ---------------------------------------------------------------------------
__global__ void finalize_kernel(const float* __restrict__ wsf,
                                float* __restrict__ out) {
    out[LOSS_OFF] = 1.25f * wsf[WS_LOSSF] / 16777216.0f;
}

extern "C" void kernel_launch(void* const* d_in, const int* in_sizes, int n_in,
                              void* d_out, int out_size, void* d_ws, size_t ws_size,
                              hipStream_t stream) {
    const float* residual = (const float*)d_in[0];
    const float* emb      = (const float*)d_in[1];
    float* out = (float*)d_out;
    char*  wsb = (char*)d_ws;
    float* wsf = (float*)d_ws;

    split_e_kernel<<<128, 256, 0, stream>>>(emb, wsb, wsf);
    norms_kernel<<<(MROWS + NCODES) / 4, 256, 0, stream>>>(residual, emb, wsf);
    gemm_kernel<<<2048, 256, 0, stream>>>(residual, wsb, wsf, out);
    argzst_kernel<<<512, 256, 0, stream>>>(residual, emb, wsf, out);
    finalize_kernel<<<1, 1, 0, stream>>>(wsf, out);
}